// Round 1
// baseline (4111.222 us; speedup 1.0000x reference)
//
#include <hip/hip_runtime.h>

// ---------------------------------------------------------------------------
// HAN link-prediction forward, fp32.
// Reference structure:
//   layer(x_p, x_a): h = x @ W + b  (per node type)
//     edge_attn over ei_pa (papers->authors) and ei_ap (authors->papers):
//       alpha[e,h] = <h_src[s],svec[h]> + <h_dst[d],dvec[h]>; leaky(0.2)
//       softmax over incoming edges per dst (segment max/sum)
//       out[d] += h_src[s] * w ; relu
//   _group with one metapath == identity (k*W/k*b/q* are dead params)
//   final: dot(z_p[eli0], z_a[eli1]) over 64 feats
// ---------------------------------------------------------------------------

#define HEADS 4

__device__ __forceinline__ float leaky02(float a) {
    return a >= 0.f ? a : 0.2f * a;
}

// order-preserving float<->uint mapping for atomicMax on floats
__device__ __forceinline__ unsigned fmap(float f) {
    unsigned b = __float_as_uint(f);
    return (b & 0x80000000u) ? ~b : (b | 0x80000000u);
}
__device__ __forceinline__ float funmap(unsigned m) {
    return __uint_as_float((m & 0x80000000u) ? (m & 0x7fffffffu) : ~m);
}

// ---------------------------------------------------------------------------
// GEMM: out[n,m] = sum_k X[n,k] * W[k,m] + b[m]; optional relu on X load.
// 256 threads; each thread computes 4 consecutive cols of one row.
// ---------------------------------------------------------------------------
template<int K, int M, bool RELU_IN>
__global__ __launch_bounds__(256) void gemm_bias(
    const float* __restrict__ X, const float* __restrict__ W,
    const float* __restrict__ b, float* __restrict__ out, int N) {
    constexpr int TPR  = M / 4;        // threads per row
    constexpr int ROWS = 256 / TPR;    // rows per block
    __shared__ float xs[ROWS][K];
    const int row0 = blockIdx.x * ROWS;

    for (int i = threadIdx.x; i < ROWS * K; i += 256) {
        int r = i / K, k = i % K;
        int gr = row0 + r;
        float v = (gr < N) ? X[(size_t)gr * K + k] : 0.f;
        if (RELU_IN) v = fmaxf(v, 0.f);
        xs[r][k] = v;
    }
    __syncthreads();

    const int r  = threadIdx.x / TPR;
    const int c0 = (threadIdx.x % TPR) * 4;
    float4 acc = make_float4(0.f, 0.f, 0.f, 0.f);
    #pragma unroll 8
    for (int k = 0; k < K; ++k) {
        float xv = xs[r][k];
        float4 wv = *(const float4*)(W + (size_t)k * M + c0);
        acc.x += xv * wv.x; acc.y += xv * wv.y;
        acc.z += xv * wv.z; acc.w += xv * wv.w;
    }
    const int gr = row0 + r;
    if (gr < N) {
        float4 bv = *(const float4*)(b + c0);
        acc.x += bv.x; acc.y += bv.y; acc.z += bv.z; acc.w += bv.w;
        *(float4*)(out + (size_t)gr * M + c0) = acc;
    }
}

// ---------------------------------------------------------------------------
// Per-node attention logits for BOTH roles of this node type:
//   asrc[n,h] = <hbuf[n, h*D:(h+1)*D], svec[h]>,  adst likewise with dvec.
// F/4 lanes per node; per-head shuffle reduction.
// ---------------------------------------------------------------------------
template<int F, int D>
__global__ __launch_bounds__(256) void node_alpha2(
    const float* __restrict__ hbuf,
    const float* __restrict__ svec, const float* __restrict__ dvec,
    float* __restrict__ asrc, float* __restrict__ adst, int N) {
    constexpr int LPN = F / 4;   // lanes per node
    constexpr int LPH = D / 4;   // lanes per head
    const int gid  = blockIdx.x * blockDim.x + threadIdx.x;
    const int node = gid / LPN;
    const int lane = gid % LPN;
    if (node >= N) return;
    const int f0 = lane * 4;
    float4 hv = *(const float4*)(hbuf + (size_t)node * F + f0);
    float4 sv = *(const float4*)(svec + f0);
    float4 dv = *(const float4*)(dvec + f0);
    float ps = hv.x * sv.x + hv.y * sv.y + hv.z * sv.z + hv.w * sv.w;
    float pd = hv.x * dv.x + hv.y * dv.y + hv.z * dv.z + hv.w * dv.w;
    #pragma unroll
    for (int off = LPH >> 1; off > 0; off >>= 1) {
        ps += __shfl_xor(ps, off);
        pd += __shfl_xor(pd, off);
    }
    if ((lane % LPH) == 0) {
        int h = lane / LPH;
        asrc[(size_t)node * HEADS + h] = ps;
        adst[(size_t)node * HEADS + h] = pd;
    }
}

// ---------------------------------------------------------------------------
// Edge pass 1: segment max of leaky(alpha) into amax (uint-mapped).
// ---------------------------------------------------------------------------
__global__ __launch_bounds__(256) void edge_max(
    const int* __restrict__ src, const int* __restrict__ dst,
    const float* __restrict__ asrc, const float* __restrict__ adst,
    unsigned* __restrict__ amax, int E) {
    const int e = blockIdx.x * blockDim.x + threadIdx.x;
    if (e >= E) return;
    const int s = src[e], d = dst[e];
    float4 as4 = *(const float4*)(asrc + (size_t)s * HEADS);
    float4 ad4 = *(const float4*)(adst + (size_t)d * HEADS);
    float a[4] = {as4.x + ad4.x, as4.y + ad4.y, as4.z + ad4.z, as4.w + ad4.w};
    #pragma unroll
    for (int h = 0; h < HEADS; ++h)
        atomicMax(amax + (size_t)d * HEADS + h, fmap(leaky02(a[h])));
}

// ---------------------------------------------------------------------------
// Edge pass 2: ex = exp(leaky(alpha) - amax[dst]); store ex; denom += ex.
// ---------------------------------------------------------------------------
__global__ __launch_bounds__(256) void edge_exp(
    const int* __restrict__ src, const int* __restrict__ dst,
    const float* __restrict__ asrc, const float* __restrict__ adst,
    const unsigned* __restrict__ amax, float* __restrict__ ex,
    float* __restrict__ denom, int E) {
    const int e = blockIdx.x * blockDim.x + threadIdx.x;
    if (e >= E) return;
    const int s = src[e], d = dst[e];
    float4 as4 = *(const float4*)(asrc + (size_t)s * HEADS);
    float4 ad4 = *(const float4*)(adst + (size_t)d * HEADS);
    uint4  am4 = *(const uint4*)(amax + (size_t)d * HEADS);
    float a[4] = {as4.x + ad4.x, as4.y + ad4.y, as4.z + ad4.z, as4.w + ad4.w};
    unsigned am[4] = {am4.x, am4.y, am4.z, am4.w};
    float exv[4];
    #pragma unroll
    for (int h = 0; h < HEADS; ++h) {
        exv[h] = __expf(leaky02(a[h]) - funmap(am[h]));
        atomicAdd(denom + (size_t)d * HEADS + h, exv[h]);
    }
    *(float4*)(ex + (size_t)e * HEADS) = make_float4(exv[0], exv[1], exv[2], exv[3]);
}

// ---------------------------------------------------------------------------
// Edge pass 3: out[d, f] += h_src[s, f] * w[h(f)];  F/4 lanes per edge.
// ---------------------------------------------------------------------------
template<int F, int D>
__global__ __launch_bounds__(256) void edge_agg(
    const int* __restrict__ src, const int* __restrict__ dst,
    const float* __restrict__ hsrc, const float* __restrict__ ex,
    const float* __restrict__ denom, float* __restrict__ out, int E) {
    constexpr int LPE = F / 4;
    const int gid  = blockIdx.x * blockDim.x + threadIdx.x;
    const int e    = gid / LPE;
    const int lane = gid % LPE;
    if (e >= E) return;
    const int s = src[e], d = dst[e];
    const int f0 = lane * 4;
    const int h  = f0 / D;
    const float w = ex[(size_t)e * HEADS + h] /
                    (denom[(size_t)d * HEADS + h] + 1e-16f);
    float4 hv = *(const float4*)(hsrc + (size_t)s * F + f0);
    float* op = out + (size_t)d * F + f0;
    atomicAdd(op + 0, hv.x * w);
    atomicAdd(op + 1, hv.y * w);
    atomicAdd(op + 2, hv.z * w);
    atomicAdd(op + 3, hv.w * w);
}

// ---------------------------------------------------------------------------
// Final: out[l] = dot(relu(zp[eli0[l]]), relu(za[eli1[l]])), 64 feats.
// ---------------------------------------------------------------------------
__global__ __launch_bounds__(256) void edge_dot(
    const int* __restrict__ eli, const float* __restrict__ zp,
    const float* __restrict__ za, float* __restrict__ out, int L) {
    constexpr int LPE = 16; // 64 floats / 4
    const int gid  = blockIdx.x * blockDim.x + threadIdx.x;
    const int e    = gid / LPE;
    const int lane = gid % LPE;
    if (e >= L) return;
    const int p = eli[e], a = eli[(size_t)L + e];
    float4 pv = *(const float4*)(zp + (size_t)p * 64 + lane * 4);
    float4 av = *(const float4*)(za + (size_t)a * 64 + lane * 4);
    float s = fmaxf(pv.x, 0.f) * fmaxf(av.x, 0.f)
            + fmaxf(pv.y, 0.f) * fmaxf(av.y, 0.f)
            + fmaxf(pv.z, 0.f) * fmaxf(av.z, 0.f)
            + fmaxf(pv.w, 0.f) * fmaxf(av.w, 0.f);
    #pragma unroll
    for (int off = 8; off > 0; off >>= 1) s += __shfl_xor(s, off);
    if (lane == 0) out[e] = s;
}

// ---------------------------------------------------------------------------
static inline int cdiv(long long a, long long b) { return (int)((a + b - 1) / b); }

extern "C" void kernel_launch(void* const* d_in, const int* in_sizes, int n_in,
                              void* d_out, int out_size, void* d_ws, size_t ws_size,
                              hipStream_t stream) {
    const float* x_p  = (const float*)d_in[0];
    const float* x_a  = (const float*)d_in[1];
    const int* ei_pa  = (const int*)d_in[2];
    const int* ei_ap  = (const int*)d_in[3];
    const int* eli    = (const int*)d_in[4];
    const float* p1W = (const float*)d_in[5];
    const float* p1b = (const float*)d_in[6];
    const float* a1W = (const float*)d_in[7];
    const float* a1b = (const float*)d_in[8];
    const float* s1pa = (const float*)d_in[9];
    const float* d1pa = (const float*)d_in[10];
    const float* s1ap = (const float*)d_in[11];
    const float* d1ap = (const float*)d_in[12];
    // 13..15: k1W, k1b, q1 — dead (single-metapath group == identity)
    const float* p2W = (const float*)d_in[16];
    const float* p2b = (const float*)d_in[17];
    const float* a2W = (const float*)d_in[18];
    const float* a2b = (const float*)d_in[19];
    const float* s2pa = (const float*)d_in[20];
    const float* d2pa = (const float*)d_in[21];
    const float* s2ap = (const float*)d_in[22];
    const float* d2ap = (const float*)d_in[23];
    // 24..26: k2W, k2b, q2 — dead

    const int NP = in_sizes[0] / 128;
    const int NA = in_sizes[1] / 128;
    const int E  = in_sizes[2] / 2;
    const int L  = in_sizes[4] / 2;
    const int N  = NP; // NP == NA == 100000

    // ---- workspace layout (with reuse; ~222 MB) ----
    char* ws = (char*)d_ws;
    size_t off = 0;
    auto alloc = [&](size_t bytes) -> char* {
        char* p = ws + off;
        off += (bytes + 255) & ~(size_t)255;
        return p;
    };
    float* regA   = (float*)alloc((size_t)N * 128 * 4);  // h_p1 ; later h_p2|h_a2
    float* regB   = (float*)alloc((size_t)N * 128 * 4);  // h_a1 ; later out_p2|out_a2
    float* out_p1 = (float*)alloc((size_t)N * 128 * 4);
    float* out_a1 = (float*)alloc((size_t)N * 128 * 4);
    float* asrc_pa = (float*)alloc((size_t)N * HEADS * 4);
    float* adst_pa = (float*)alloc((size_t)N * HEADS * 4);
    float* asrc_ap = (float*)alloc((size_t)N * HEADS * 4);
    float* adst_ap = (float*)alloc((size_t)N * HEADS * 4);
    unsigned* amax = (unsigned*)alloc((size_t)N * HEADS * 4);
    float* denom   = (float*)alloc((size_t)N * HEADS * 4);
    float* exbuf   = (float*)alloc((size_t)E * HEADS * 4);

    float* h_p1 = regA;
    float* h_a1 = regB;
    float* h_p2 = regA;                     // reuses dead h_p1
    float* h_a2 = regA + (size_t)N * 64;
    float* out_p2 = regB;                   // reuses dead h_a1
    float* out_a2 = regB + (size_t)N * 64;

    const int* src_pa = ei_pa;           // papers
    const int* dst_pa = ei_pa + E;       // authors
    const int* src_ap = ei_ap;           // authors
    const int* dst_ap = ei_ap + E;       // papers

    // ================= Layer 1 =================
    gemm_bias<128, 128, false><<<cdiv(NP, 8), 256, 0, stream>>>(x_p, p1W, p1b, h_p1, NP);
    gemm_bias<128, 128, false><<<cdiv(NA, 8), 256, 0, stream>>>(x_a, a1W, a1b, h_a1, NA);

    // paper nodes: src role for pa (s1pa), dst role for ap (d1ap)
    node_alpha2<128, 32><<<cdiv((long long)NP * 32, 256), 256, 0, stream>>>(
        h_p1, s1pa, d1ap, asrc_pa, adst_ap, NP);
    // author nodes: src role for ap (s1ap), dst role for pa (d1pa)
    node_alpha2<128, 32><<<cdiv((long long)NA * 32, 256), 256, 0, stream>>>(
        h_a1, s1ap, d1pa, asrc_ap, adst_pa, NA);

    // ---- pass pa: papers -> authors, output out_a1 ----
    hipMemsetAsync(amax, 0, (size_t)N * HEADS * 4, stream);
    hipMemsetAsync(denom, 0, (size_t)N * HEADS * 4, stream);
    hipMemsetAsync(out_a1, 0, (size_t)N * 128 * 4, stream);
    edge_max<<<cdiv(E, 256), 256, 0, stream>>>(src_pa, dst_pa, asrc_pa, adst_pa, amax, E);
    edge_exp<<<cdiv(E, 256), 256, 0, stream>>>(src_pa, dst_pa, asrc_pa, adst_pa, amax, exbuf, denom, E);
    edge_agg<128, 32><<<cdiv((long long)E * 32, 256), 256, 0, stream>>>(
        src_pa, dst_pa, h_p1, exbuf, denom, out_a1, E);

    // ---- pass ap: authors -> papers, output out_p1 ----
    hipMemsetAsync(amax, 0, (size_t)N * HEADS * 4, stream);
    hipMemsetAsync(denom, 0, (size_t)N * HEADS * 4, stream);
    hipMemsetAsync(out_p1, 0, (size_t)N * 128 * 4, stream);
    edge_max<<<cdiv(E, 256), 256, 0, stream>>>(src_ap, dst_ap, asrc_ap, adst_ap, amax, E);
    edge_exp<<<cdiv(E, 256), 256, 0, stream>>>(src_ap, dst_ap, asrc_ap, adst_ap, amax, exbuf, denom, E);
    edge_agg<128, 32><<<cdiv((long long)E * 32, 256), 256, 0, stream>>>(
        src_ap, dst_ap, h_a1, exbuf, denom, out_p1, E);

    // ================= Layer 2 =================
    // h2 = relu(out1) @ W2 + b2   (relu fused into GEMM input load)
    gemm_bias<128, 64, true><<<cdiv(NP, 16), 256, 0, stream>>>(out_p1, p2W, p2b, h_p2, NP);
    gemm_bias<128, 64, true><<<cdiv(NA, 16), 256, 0, stream>>>(out_a1, a2W, a2b, h_a2, NA);

    node_alpha2<64, 16><<<cdiv((long long)NP * 16, 256), 256, 0, stream>>>(
        h_p2, s2pa, d2ap, asrc_pa, adst_ap, NP);
    node_alpha2<64, 16><<<cdiv((long long)NA * 16, 256), 256, 0, stream>>>(
        h_a2, s2ap, d2pa, asrc_ap, adst_pa, NA);

    // ---- pass pa L2: output out_a2 ----
    hipMemsetAsync(amax, 0, (size_t)N * HEADS * 4, stream);
    hipMemsetAsync(denom, 0, (size_t)N * HEADS * 4, stream);
    hipMemsetAsync(out_a2, 0, (size_t)N * 64 * 4, stream);
    edge_max<<<cdiv(E, 256), 256, 0, stream>>>(src_pa, dst_pa, asrc_pa, adst_pa, amax, E);
    edge_exp<<<cdiv(E, 256), 256, 0, stream>>>(src_pa, dst_pa, asrc_pa, adst_pa, amax, exbuf, denom, E);
    edge_agg<64, 16><<<cdiv((long long)E * 16, 256), 256, 0, stream>>>(
        src_pa, dst_pa, h_p2, exbuf, denom, out_a2, E);

    // ---- pass ap L2: output out_p2 ----
    hipMemsetAsync(amax, 0, (size_t)N * HEADS * 4, stream);
    hipMemsetAsync(denom, 0, (size_t)N * HEADS * 4, stream);
    hipMemsetAsync(out_p2, 0, (size_t)N * 64 * 4, stream);
    edge_max<<<cdiv(E, 256), 256, 0, stream>>>(src_ap, dst_ap, asrc_ap, adst_ap, amax, E);
    edge_exp<<<cdiv(E, 256), 256, 0, stream>>>(src_ap, dst_ap, asrc_ap, adst_ap, amax, exbuf, denom, E);
    edge_agg<64, 16><<<cdiv((long long)E * 16, 256), 256, 0, stream>>>(
        src_ap, dst_ap, h_a2, exbuf, denom, out_p2, E);

    // ================= Final dot =================
    edge_dot<<<cdiv((long long)L * 16, 256), 256, 0, stream>>>(
        eli, out_p2, out_a2, (float*)d_out, L);
}

// Round 2
// 1090.325 us; speedup vs baseline: 3.7706x; 3.7706x over previous
//
#include <hip/hip_runtime.h>

// ---------------------------------------------------------------------------
// HAN link-prediction forward, fp32, CSR-based edge softmax/aggregation.
//   - _group with one metapath == identity (k*W/k*b/q* are dead params)
//   - CSR (offsets/counts/perm) built per edge list, reused by both layers
//   - per-dst-node fused softmax+aggregate: no float atomics, 1 write/row
// ---------------------------------------------------------------------------

#define HEADS 4

__device__ __forceinline__ float leaky02(float a) {
    return a >= 0.f ? a : 0.2f * a;
}

// ---------------------------------------------------------------------------
// GEMM: out[n,m] = sum_k X[n,k] * W[k,m] + b[m]; optional relu on X load.
// ---------------------------------------------------------------------------
template<int K, int M, bool RELU_IN>
__global__ __launch_bounds__(256) void gemm_bias(
    const float* __restrict__ X, const float* __restrict__ W,
    const float* __restrict__ b, float* __restrict__ out, int N) {
    constexpr int TPR  = M / 4;
    constexpr int ROWS = 256 / TPR;
    __shared__ float xs[ROWS][K];
    const int row0 = blockIdx.x * ROWS;

    for (int i = threadIdx.x; i < ROWS * K; i += 256) {
        int r = i / K, k = i % K;
        int gr = row0 + r;
        float v = (gr < N) ? X[(size_t)gr * K + k] : 0.f;
        if (RELU_IN) v = fmaxf(v, 0.f);
        xs[r][k] = v;
    }
    __syncthreads();

    const int r  = threadIdx.x / TPR;
    const int c0 = (threadIdx.x % TPR) * 4;
    float4 acc = make_float4(0.f, 0.f, 0.f, 0.f);
    #pragma unroll 8
    for (int k = 0; k < K; ++k) {
        float xv = xs[r][k];
        float4 wv = *(const float4*)(W + (size_t)k * M + c0);
        acc.x += xv * wv.x; acc.y += xv * wv.y;
        acc.z += xv * wv.z; acc.w += xv * wv.w;
    }
    const int gr = row0 + r;
    if (gr < N) {
        float4 bv = *(const float4*)(b + c0);
        acc.x += bv.x; acc.y += bv.y; acc.z += bv.z; acc.w += bv.w;
        *(float4*)(out + (size_t)gr * M + c0) = acc;
    }
}

// ---------------------------------------------------------------------------
// Per-node attention logits for both roles of this node type.
// ---------------------------------------------------------------------------
template<int F, int D>
__global__ __launch_bounds__(256) void node_alpha2(
    const float* __restrict__ hbuf,
    const float* __restrict__ svec, const float* __restrict__ dvec,
    float* __restrict__ asrc, float* __restrict__ adst, int N) {
    constexpr int LPN = F / 4;
    constexpr int LPH = D / 4;
    const int gid  = blockIdx.x * blockDim.x + threadIdx.x;
    const int node = gid / LPN;
    const int lane = gid % LPN;
    if (node >= N) return;
    const int f0 = lane * 4;
    float4 hv = *(const float4*)(hbuf + (size_t)node * F + f0);
    float4 sv = *(const float4*)(svec + f0);
    float4 dv = *(const float4*)(dvec + f0);
    float ps = hv.x * sv.x + hv.y * sv.y + hv.z * sv.z + hv.w * sv.w;
    float pd = hv.x * dv.x + hv.y * dv.y + hv.z * dv.z + hv.w * dv.w;
    #pragma unroll
    for (int off = LPH >> 1; off > 0; off >>= 1) {
        ps += __shfl_xor(ps, off);
        pd += __shfl_xor(pd, off);
    }
    if ((lane % LPH) == 0) {
        int h = lane / LPH;
        asrc[(size_t)node * HEADS + h] = ps;
        adst[(size_t)node * HEADS + h] = pd;
    }
}

// ---------------------------------------------------------------------------
// CSR build: histogram -> exclusive scan -> scatter permutation.
// ---------------------------------------------------------------------------
__global__ __launch_bounds__(256) void hist_kernel(
    const int* __restrict__ dst, int* __restrict__ counts, int E) {
    const int e = blockIdx.x * 256 + threadIdx.x;
    if (e < E) atomicAdd(counts + dst[e], 1);
}

__global__ __launch_bounds__(256) void scan_blk(
    const int* __restrict__ in, int* __restrict__ out,
    int* __restrict__ bsum, int N) {
    __shared__ int sh[256];
    const int base = blockIdx.x * 1024 + threadIdx.x * 4;
    int v[4]; int s = 0;
    #pragma unroll
    for (int j = 0; j < 4; ++j) { v[j] = (base + j < N) ? in[base + j] : 0; s += v[j]; }
    sh[threadIdx.x] = s;
    __syncthreads();
    for (int off = 1; off < 256; off <<= 1) {
        int t = (threadIdx.x >= off) ? sh[threadIdx.x - off] : 0;
        __syncthreads();
        sh[threadIdx.x] += t;
        __syncthreads();
    }
    int run = sh[threadIdx.x] - s;  // exclusive prefix of this thread
    #pragma unroll
    for (int j = 0; j < 4; ++j) {
        if (base + j < N) out[base + j] = run;
        run += v[j];
    }
    if (threadIdx.x == 255) bsum[blockIdx.x] = sh[255];
}

__global__ __launch_bounds__(256) void scan_sums(int* __restrict__ bsum, int nb) {
    __shared__ int sh[256];
    int v = (threadIdx.x < nb) ? bsum[threadIdx.x] : 0;
    sh[threadIdx.x] = v;
    __syncthreads();
    for (int off = 1; off < 256; off <<= 1) {
        int t = (threadIdx.x >= off) ? sh[threadIdx.x - off] : 0;
        __syncthreads();
        sh[threadIdx.x] += t;
        __syncthreads();
    }
    if (threadIdx.x < nb) bsum[threadIdx.x] = sh[threadIdx.x] - v;  // exclusive
}

__global__ __launch_bounds__(256) void scan_add(
    int* __restrict__ out, const int* __restrict__ bsum, int N) {
    const int base = blockIdx.x * 1024 + threadIdx.x * 4;
    const int add = bsum[blockIdx.x];
    #pragma unroll
    for (int j = 0; j < 4; ++j)
        if (base + j < N) out[base + j] += add;
}

__global__ __launch_bounds__(256) void scatter_perm(
    const int* __restrict__ src, const int* __restrict__ dst,
    const int* __restrict__ offsets, int* __restrict__ cursor,
    int* __restrict__ perm, int E) {
    const int e = blockIdx.x * 256 + threadIdx.x;
    if (e >= E) return;
    const int d = dst[e];
    const int pos = offsets[d] + atomicAdd(cursor + d, 1);
    perm[pos] = src[e];
}

// ---------------------------------------------------------------------------
// Fused per-dst softmax + aggregation over CSR segments.
// F/4 lanes per node; lane's head h = (lane*4)/D.
//   pass 1: max over leaky(asrc[s,h] + adst[d,h])
//   pass 2: ex = exp(a - mx); den += ex; acc += ex * h_src[s, f0..f0+3]
//   out[d] = relu(acc / (den + 1e-16))
// ---------------------------------------------------------------------------
template<int F, int D>
__global__ __launch_bounds__(256) void csr_attn_agg(
    const int* __restrict__ perm, const int* __restrict__ offsets,
    const int* __restrict__ counts,
    const float* __restrict__ asrc, const float* __restrict__ adst,
    const float* __restrict__ hsrc, float* __restrict__ out, int N) {
    constexpr int LPN = F / 4;
    const int gid  = blockIdx.x * 256 + threadIdx.x;
    const int node = gid / LPN;
    const int lane = gid % LPN;
    if (node >= N) return;
    const int start = offsets[node];
    const int cnt   = counts[node];
    const int f0 = lane * 4;
    const int h  = f0 / D;
    const float ad = adst[(size_t)node * HEADS + h];

    float mx = -INFINITY;
    for (int i = 0; i < cnt; ++i) {
        int s = perm[start + i];
        float a = leaky02(asrc[(size_t)s * HEADS + h] + ad);
        mx = fmaxf(mx, a);
    }

    float den = 0.f;
    float4 acc = make_float4(0.f, 0.f, 0.f, 0.f);
    for (int i = 0; i < cnt; ++i) {
        int s = perm[start + i];
        float a = leaky02(asrc[(size_t)s * HEADS + h] + ad);
        float ex = __expf(a - mx);
        den += ex;
        float4 hv = *(const float4*)(hsrc + (size_t)s * F + f0);
        acc.x += ex * hv.x; acc.y += ex * hv.y;
        acc.z += ex * hv.z; acc.w += ex * hv.w;
    }
    const float inv = 1.f / (den + 1e-16f);
    float4 o;
    o.x = fmaxf(acc.x * inv, 0.f);
    o.y = fmaxf(acc.y * inv, 0.f);
    o.z = fmaxf(acc.z * inv, 0.f);
    o.w = fmaxf(acc.w * inv, 0.f);
    *(float4*)(out + (size_t)node * F + f0) = o;
}

// ---------------------------------------------------------------------------
// Final: out[l] = dot(zp[eli0[l]], za[eli1[l]]), 64 feats (inputs already relu'd).
// ---------------------------------------------------------------------------
__global__ __launch_bounds__(256) void edge_dot(
    const int* __restrict__ eli, const float* __restrict__ zp,
    const float* __restrict__ za, float* __restrict__ out, int L) {
    constexpr int LPE = 16;
    const int gid  = blockIdx.x * blockDim.x + threadIdx.x;
    const int e    = gid / LPE;
    const int lane = gid % LPE;
    if (e >= L) return;
    const int p = eli[e], a = eli[(size_t)L + e];
    float4 pv = *(const float4*)(zp + (size_t)p * 64 + lane * 4);
    float4 av = *(const float4*)(za + (size_t)a * 64 + lane * 4);
    float s = pv.x * av.x + pv.y * av.y + pv.z * av.z + pv.w * av.w;
    #pragma unroll
    for (int off = 8; off > 0; off >>= 1) s += __shfl_xor(s, off);
    if (lane == 0) out[e] = s;
}

// ---------------------------------------------------------------------------
static inline int cdiv(long long a, long long b) { return (int)((a + b - 1) / b); }

extern "C" void kernel_launch(void* const* d_in, const int* in_sizes, int n_in,
                              void* d_out, int out_size, void* d_ws, size_t ws_size,
                              hipStream_t stream) {
    const float* x_p  = (const float*)d_in[0];
    const float* x_a  = (const float*)d_in[1];
    const int* ei_pa  = (const int*)d_in[2];
    const int* ei_ap  = (const int*)d_in[3];
    const int* eli    = (const int*)d_in[4];
    const float* p1W = (const float*)d_in[5];
    const float* p1b = (const float*)d_in[6];
    const float* a1W = (const float*)d_in[7];
    const float* a1b = (const float*)d_in[8];
    const float* s1pa = (const float*)d_in[9];
    const float* d1pa = (const float*)d_in[10];
    const float* s1ap = (const float*)d_in[11];
    const float* d1ap = (const float*)d_in[12];
    // 13..15: k1W, k1b, q1 — dead (single-metapath group == identity)
    const float* p2W = (const float*)d_in[16];
    const float* p2b = (const float*)d_in[17];
    const float* a2W = (const float*)d_in[18];
    const float* a2b = (const float*)d_in[19];
    const float* s2pa = (const float*)d_in[20];
    const float* d2pa = (const float*)d_in[21];
    const float* s2ap = (const float*)d_in[22];
    const float* d2ap = (const float*)d_in[23];
    // 24..26: k2W, k2b, q2 — dead

    const int NP = in_sizes[0] / 128;
    const int NA = in_sizes[1] / 128;
    const int E  = in_sizes[2] / 2;
    const int L  = in_sizes[4] / 2;
    const int N  = NP;  // NP == NA

    // ---- workspace layout ----
    char* ws = (char*)d_ws;
    size_t off = 0;
    auto alloc = [&](size_t bytes) -> char* {
        char* p = ws + off;
        off += (bytes + 255) & ~(size_t)255;
        return p;
    };
    float* regA   = (float*)alloc((size_t)N * 128 * 4);  // h_p1 ; later h_p2|h_a2
    float* regB   = (float*)alloc((size_t)N * 128 * 4);  // h_a1 ; later out_p2|out_a2
    float* out_p1 = (float*)alloc((size_t)N * 128 * 4);
    float* out_a1 = (float*)alloc((size_t)N * 128 * 4);
    float* asrc_pa = (float*)alloc((size_t)N * HEADS * 4);
    float* adst_pa = (float*)alloc((size_t)N * HEADS * 4);
    float* asrc_ap = (float*)alloc((size_t)N * HEADS * 4);
    float* adst_ap = (float*)alloc((size_t)N * HEADS * 4);
    // CSR structures (layer-independent)
    int* cnt_pa = (int*)alloc((size_t)N * 4);
    int* off_pa = (int*)alloc((size_t)N * 4);
    int* perm_pa = (int*)alloc((size_t)E * 4);
    int* cnt_ap = (int*)alloc((size_t)N * 4);
    int* off_ap = (int*)alloc((size_t)N * 4);
    int* perm_ap = (int*)alloc((size_t)E * 4);
    int* cursor  = (int*)alloc((size_t)N * 4);
    int* bsum    = (int*)alloc(256 * 4);

    float* h_p1 = regA;
    float* h_a1 = regB;
    float* h_p2 = regA;
    float* h_a2 = regA + (size_t)N * 64;
    float* out_p2 = regB;
    float* out_a2 = regB + (size_t)N * 64;

    const int* src_pa = ei_pa;       // papers
    const int* dst_pa = ei_pa + E;   // authors
    const int* src_ap = ei_ap;       // authors
    const int* dst_ap = ei_ap + E;   // papers

    const int nbScan = cdiv(N, 1024);

    // ================= CSR build (both lists) =================
    hipMemsetAsync(cnt_pa, 0, (size_t)N * 4, stream);
    hist_kernel<<<cdiv(E, 256), 256, 0, stream>>>(dst_pa, cnt_pa, E);
    scan_blk<<<nbScan, 256, 0, stream>>>(cnt_pa, off_pa, bsum, N);
    scan_sums<<<1, 256, 0, stream>>>(bsum, nbScan);
    scan_add<<<nbScan, 256, 0, stream>>>(off_pa, bsum, N);
    hipMemsetAsync(cursor, 0, (size_t)N * 4, stream);
    scatter_perm<<<cdiv(E, 256), 256, 0, stream>>>(src_pa, dst_pa, off_pa, cursor, perm_pa, E);

    hipMemsetAsync(cnt_ap, 0, (size_t)N * 4, stream);
    hist_kernel<<<cdiv(E, 256), 256, 0, stream>>>(dst_ap, cnt_ap, E);
    scan_blk<<<nbScan, 256, 0, stream>>>(cnt_ap, off_ap, bsum, N);
    scan_sums<<<1, 256, 0, stream>>>(bsum, nbScan);
    scan_add<<<nbScan, 256, 0, stream>>>(off_ap, bsum, N);
    hipMemsetAsync(cursor, 0, (size_t)N * 4, stream);
    scatter_perm<<<cdiv(E, 256), 256, 0, stream>>>(src_ap, dst_ap, off_ap, cursor, perm_ap, E);

    // ================= Layer 1 =================
    gemm_bias<128, 128, false><<<cdiv(NP, 8), 256, 0, stream>>>(x_p, p1W, p1b, h_p1, NP);
    gemm_bias<128, 128, false><<<cdiv(NA, 8), 256, 0, stream>>>(x_a, a1W, a1b, h_a1, NA);

    node_alpha2<128, 32><<<cdiv((long long)NP * 32, 256), 256, 0, stream>>>(
        h_p1, s1pa, d1ap, asrc_pa, adst_ap, NP);
    node_alpha2<128, 32><<<cdiv((long long)NA * 32, 256), 256, 0, stream>>>(
        h_a1, s1ap, d1pa, asrc_ap, adst_pa, NA);

    // pa: papers -> authors (out_a1); ap: authors -> papers (out_p1)
    csr_attn_agg<128, 32><<<cdiv((long long)N * 32, 256), 256, 0, stream>>>(
        perm_pa, off_pa, cnt_pa, asrc_pa, adst_pa, h_p1, out_a1, N);
    csr_attn_agg<128, 32><<<cdiv((long long)N * 32, 256), 256, 0, stream>>>(
        perm_ap, off_ap, cnt_ap, asrc_ap, adst_ap, h_a1, out_p1, N);

    // ================= Layer 2 =================
    gemm_bias<128, 64, true><<<cdiv(NP, 16), 256, 0, stream>>>(out_p1, p2W, p2b, h_p2, NP);
    gemm_bias<128, 64, true><<<cdiv(NA, 16), 256, 0, stream>>>(out_a1, a2W, a2b, h_a2, NA);

    node_alpha2<64, 16><<<cdiv((long long)NP * 16, 256), 256, 0, stream>>>(
        h_p2, s2pa, d2ap, asrc_pa, adst_ap, NP);
    node_alpha2<64, 16><<<cdiv((long long)NA * 16, 256), 256, 0, stream>>>(
        h_a2, s2ap, d2pa, asrc_ap, adst_pa, NA);

    csr_attn_agg<64, 16><<<cdiv((long long)N * 16, 256), 256, 0, stream>>>(
        perm_pa, off_pa, cnt_pa, asrc_pa, adst_pa, h_p2, out_a2, N);
    csr_attn_agg<64, 16><<<cdiv((long long)N * 16, 256), 256, 0, stream>>>(
        perm_ap, off_ap, cnt_ap, asrc_ap, adst_ap, h_a2, out_p2, N);

    // ================= Final dot =================
    edge_dot<<<cdiv((long long)L * 16, 256), 256, 0, stream>>>(
        eli, out_p2, out_a2, (float*)d_out, L);
}

// Round 3
// 740.590 us; speedup vs baseline: 5.5513x; 1.4722x over previous
//
#include <hip/hip_runtime.h>

// ---------------------------------------------------------------------------
// HAN link-prediction forward, fp32, CSR-based edge softmax/aggregation.
//   - _group with one metapath == identity (k*W/k*b/q* are dead params)
//   - CSR (offsets/counts/perm) built per edge list, reused by both layers
//   - per-dst-node fused softmax+aggregate: no float atomics, 1 write/row
//   - register-tiled GEMM: 64xM block tile, K-major LDS for X, TM rows/thread
// ---------------------------------------------------------------------------

#define HEADS 4

__device__ __forceinline__ float leaky02(float a) {
    return a >= 0.f ? a : 0.2f * a;
}

// ---------------------------------------------------------------------------
// GEMM: out[n,m] = sum_k X[n,k] * W[k,m] + b[m].
// 256 threads; block tile = 64 rows x M cols; thread tile = TM rows x 4 cols.
// X staged K-major in LDS (xs[k][row]) so per-k row reads are ds_read_b128
// broadcasts; W rows read per-k as coalesced float4 (64KB, L1/L2-hot).
// ---------------------------------------------------------------------------
template<int K, int M, int TM>
__global__ __launch_bounds__(256) void gemm_bias(
    const float* __restrict__ X, const float* __restrict__ W,
    const float* __restrict__ b, float* __restrict__ out, int N) {
    constexpr int TPC  = M / 4;            // thread col-groups
    constexpr int RG   = 256 / TPC;        // row-groups
    constexpr int ROWS = RG * TM;          // 64 for both configs
    static_assert(ROWS == 64, "tile rows");
    __shared__ float xs[K][ROWS + 1];

    const int row0 = blockIdx.x * ROWS;

    // stage X[row0..row0+63][0..K) -> xs[k][r] (transposed)
    #pragma unroll
    for (int i = 0; i < (ROWS * K) / (256 * 4); ++i) {
        const int r  = i * 8 + (threadIdx.x >> 5);
        const int k0 = (threadIdx.x & 31) * 4;
        const int gr = row0 + r;
        float4 v = (gr < N) ? *(const float4*)(X + (size_t)gr * K + k0)
                            : make_float4(0.f, 0.f, 0.f, 0.f);
        xs[k0 + 0][r] = v.x;
        xs[k0 + 1][r] = v.y;
        xs[k0 + 2][r] = v.z;
        xs[k0 + 3][r] = v.w;
    }
    __syncthreads();

    const int col0 = (threadIdx.x % TPC) * 4;
    const int r0   = (threadIdx.x / TPC) * TM;

    float4 acc[TM];
    #pragma unroll
    for (int j = 0; j < TM; ++j) acc[j] = make_float4(0.f, 0.f, 0.f, 0.f);

    #pragma unroll 4
    for (int k = 0; k < K; ++k) {
        const float4 wv = *(const float4*)(W + (size_t)k * M + col0);
        float xr[TM];
        #pragma unroll
        for (int j4 = 0; j4 < TM / 4; ++j4) {
            float4 xv = *(const float4*)(&xs[k][r0 + j4 * 4]);
            xr[j4 * 4 + 0] = xv.x; xr[j4 * 4 + 1] = xv.y;
            xr[j4 * 4 + 2] = xv.z; xr[j4 * 4 + 3] = xv.w;
        }
        #pragma unroll
        for (int j = 0; j < TM; ++j) {
            acc[j].x += xr[j] * wv.x; acc[j].y += xr[j] * wv.y;
            acc[j].z += xr[j] * wv.z; acc[j].w += xr[j] * wv.w;
        }
    }

    const float4 bv = *(const float4*)(b + col0);
    #pragma unroll
    for (int j = 0; j < TM; ++j) {
        const int gr = row0 + r0 + j;
        if (gr < N) {
            float4 o;
            o.x = acc[j].x + bv.x; o.y = acc[j].y + bv.y;
            o.z = acc[j].z + bv.z; o.w = acc[j].w + bv.w;
            *(float4*)(out + (size_t)gr * M + col0) = o;
        }
    }
}

// ---------------------------------------------------------------------------
// Per-node attention logits for both roles of this node type.
// ---------------------------------------------------------------------------
template<int F, int D>
__global__ __launch_bounds__(256) void node_alpha2(
    const float* __restrict__ hbuf,
    const float* __restrict__ svec, const float* __restrict__ dvec,
    float* __restrict__ asrc, float* __restrict__ adst, int N) {
    constexpr int LPN = F / 4;
    constexpr int LPH = D / 4;
    const int gid  = blockIdx.x * blockDim.x + threadIdx.x;
    const int node = gid / LPN;
    const int lane = gid % LPN;
    if (node >= N) return;
    const int f0 = lane * 4;
    float4 hv = *(const float4*)(hbuf + (size_t)node * F + f0);
    float4 sv = *(const float4*)(svec + f0);
    float4 dv = *(const float4*)(dvec + f0);
    float ps = hv.x * sv.x + hv.y * sv.y + hv.z * sv.z + hv.w * sv.w;
    float pd = hv.x * dv.x + hv.y * dv.y + hv.z * dv.z + hv.w * dv.w;
    #pragma unroll
    for (int off = LPH >> 1; off > 0; off >>= 1) {
        ps += __shfl_xor(ps, off);
        pd += __shfl_xor(pd, off);
    }
    if ((lane % LPH) == 0) {
        int h = lane / LPH;
        asrc[(size_t)node * HEADS + h] = ps;
        adst[(size_t)node * HEADS + h] = pd;
    }
}

// ---------------------------------------------------------------------------
// CSR build: histogram -> exclusive scan -> scatter permutation.
// ---------------------------------------------------------------------------
__global__ __launch_bounds__(256) void hist_kernel(
    const int* __restrict__ dst, int* __restrict__ counts, int E) {
    const int e = blockIdx.x * 256 + threadIdx.x;
    if (e < E) atomicAdd(counts + dst[e], 1);
}

__global__ __launch_bounds__(256) void scan_blk(
    const int* __restrict__ in, int* __restrict__ out,
    int* __restrict__ bsum, int N) {
    __shared__ int sh[256];
    const int base = blockIdx.x * 1024 + threadIdx.x * 4;
    int v[4]; int s = 0;
    #pragma unroll
    for (int j = 0; j < 4; ++j) { v[j] = (base + j < N) ? in[base + j] : 0; s += v[j]; }
    sh[threadIdx.x] = s;
    __syncthreads();
    for (int off = 1; off < 256; off <<= 1) {
        int t = (threadIdx.x >= off) ? sh[threadIdx.x - off] : 0;
        __syncthreads();
        sh[threadIdx.x] += t;
        __syncthreads();
    }
    int run = sh[threadIdx.x] - s;  // exclusive prefix of this thread
    #pragma unroll
    for (int j = 0; j < 4; ++j) {
        if (base + j < N) out[base + j] = run;
        run += v[j];
    }
    if (threadIdx.x == 255) bsum[blockIdx.x] = sh[255];
}

__global__ __launch_bounds__(256) void scan_sums(int* __restrict__ bsum, int nb) {
    __shared__ int sh[256];
    int v = (threadIdx.x < nb) ? bsum[threadIdx.x] : 0;
    sh[threadIdx.x] = v;
    __syncthreads();
    for (int off = 1; off < 256; off <<= 1) {
        int t = (threadIdx.x >= off) ? sh[threadIdx.x - off] : 0;
        __syncthreads();
        sh[threadIdx.x] += t;
        __syncthreads();
    }
    if (threadIdx.x < nb) bsum[threadIdx.x] = sh[threadIdx.x] - v;  // exclusive
}

__global__ __launch_bounds__(256) void scan_add(
    int* __restrict__ out, const int* __restrict__ bsum, int N) {
    const int base = blockIdx.x * 1024 + threadIdx.x * 4;
    const int add = bsum[blockIdx.x];
    #pragma unroll
    for (int j = 0; j < 4; ++j)
        if (base + j < N) out[base + j] += add;
}

__global__ __launch_bounds__(256) void scatter_perm(
    const int* __restrict__ src, const int* __restrict__ dst,
    const int* __restrict__ offsets, int* __restrict__ cursor,
    int* __restrict__ perm, int E) {
    const int e = blockIdx.x * 256 + threadIdx.x;
    if (e >= E) return;
    const int d = dst[e];
    const int pos = offsets[d] + atomicAdd(cursor + d, 1);
    perm[pos] = src[e];
}

// ---------------------------------------------------------------------------
// Fused per-dst softmax + aggregation over CSR segments.
// ---------------------------------------------------------------------------
template<int F, int D>
__global__ __launch_bounds__(256) void csr_attn_agg(
    const int* __restrict__ perm, const int* __restrict__ offsets,
    const int* __restrict__ counts,
    const float* __restrict__ asrc, const float* __restrict__ adst,
    const float* __restrict__ hsrc, float* __restrict__ out, int N) {
    constexpr int LPN = F / 4;
    const int gid  = blockIdx.x * 256 + threadIdx.x;
    const int node = gid / LPN;
    const int lane = gid % LPN;
    if (node >= N) return;
    const int start = offsets[node];
    const int cnt   = counts[node];
    const int f0 = lane * 4;
    const int h  = f0 / D;
    const float ad = adst[(size_t)node * HEADS + h];

    float mx = -INFINITY;
    for (int i = 0; i < cnt; ++i) {
        int s = perm[start + i];
        float a = leaky02(asrc[(size_t)s * HEADS + h] + ad);
        mx = fmaxf(mx, a);
    }

    float den = 0.f;
    float4 acc = make_float4(0.f, 0.f, 0.f, 0.f);
    for (int i = 0; i < cnt; ++i) {
        int s = perm[start + i];
        float a = leaky02(asrc[(size_t)s * HEADS + h] + ad);
        float ex = __expf(a - mx);
        den += ex;
        float4 hv = *(const float4*)(hsrc + (size_t)s * F + f0);
        acc.x += ex * hv.x; acc.y += ex * hv.y;
        acc.z += ex * hv.z; acc.w += ex * hv.w;
    }
    const float inv = 1.f / (den + 1e-16f);
    float4 o;
    o.x = fmaxf(acc.x * inv, 0.f);
    o.y = fmaxf(acc.y * inv, 0.f);
    o.z = fmaxf(acc.z * inv, 0.f);
    o.w = fmaxf(acc.w * inv, 0.f);
    *(float4*)(out + (size_t)node * F + f0) = o;
}

// ---------------------------------------------------------------------------
// Final: out[l] = dot(zp[eli0[l]], za[eli1[l]]), 64 feats (already relu'd).
// ---------------------------------------------------------------------------
__global__ __launch_bounds__(256) void edge_dot(
    const int* __restrict__ eli, const float* __restrict__ zp,
    const float* __restrict__ za, float* __restrict__ out, int L) {
    constexpr int LPE = 16;
    const int gid  = blockIdx.x * blockDim.x + threadIdx.x;
    const int e    = gid / LPE;
    const int lane = gid % LPE;
    if (e >= L) return;
    const int p = eli[e], a = eli[(size_t)L + e];
    float4 pv = *(const float4*)(zp + (size_t)p * 64 + lane * 4);
    float4 av = *(const float4*)(za + (size_t)a * 64 + lane * 4);
    float s = pv.x * av.x + pv.y * av.y + pv.z * av.z + pv.w * av.w;
    #pragma unroll
    for (int off = 8; off > 0; off >>= 1) s += __shfl_xor(s, off);
    if (lane == 0) out[e] = s;
}

// ---------------------------------------------------------------------------
static inline int cdiv(long long a, long long b) { return (int)((a + b - 1) / b); }

extern "C" void kernel_launch(void* const* d_in, const int* in_sizes, int n_in,
                              void* d_out, int out_size, void* d_ws, size_t ws_size,
                              hipStream_t stream) {
    const float* x_p  = (const float*)d_in[0];
    const float* x_a  = (const float*)d_in[1];
    const int* ei_pa  = (const int*)d_in[2];
    const int* ei_ap  = (const int*)d_in[3];
    const int* eli    = (const int*)d_in[4];
    const float* p1W = (const float*)d_in[5];
    const float* p1b = (const float*)d_in[6];
    const float* a1W = (const float*)d_in[7];
    const float* a1b = (const float*)d_in[8];
    const float* s1pa = (const float*)d_in[9];
    const float* d1pa = (const float*)d_in[10];
    const float* s1ap = (const float*)d_in[11];
    const float* d1ap = (const float*)d_in[12];
    // 13..15: k1W, k1b, q1 — dead (single-metapath group == identity)
    const float* p2W = (const float*)d_in[16];
    const float* p2b = (const float*)d_in[17];
    const float* a2W = (const float*)d_in[18];
    const float* a2b = (const float*)d_in[19];
    const float* s2pa = (const float*)d_in[20];
    const float* d2pa = (const float*)d_in[21];
    const float* s2ap = (const float*)d_in[22];
    const float* d2ap = (const float*)d_in[23];
    // 24..26: k2W, k2b, q2 — dead

    const int NP = in_sizes[0] / 128;
    const int NA = in_sizes[1] / 128;
    const int E  = in_sizes[2] / 2;
    const int L  = in_sizes[4] / 2;
    const int N  = NP;  // NP == NA

    // ---- workspace layout ----
    char* ws = (char*)d_ws;
    size_t off = 0;
    auto alloc = [&](size_t bytes) -> char* {
        char* p = ws + off;
        off += (bytes + 255) & ~(size_t)255;
        return p;
    };
    float* regA   = (float*)alloc((size_t)N * 128 * 4);  // h_p1 ; later h_p2|h_a2
    float* regB   = (float*)alloc((size_t)N * 128 * 4);  // h_a1 ; later out_p2|out_a2
    float* out_p1 = (float*)alloc((size_t)N * 128 * 4);
    float* out_a1 = (float*)alloc((size_t)N * 128 * 4);
    float* asrc_pa = (float*)alloc((size_t)N * HEADS * 4);
    float* adst_pa = (float*)alloc((size_t)N * HEADS * 4);
    float* asrc_ap = (float*)alloc((size_t)N * HEADS * 4);
    float* adst_ap = (float*)alloc((size_t)N * HEADS * 4);
    // CSR structures (layer-independent)
    int* cnt_pa = (int*)alloc((size_t)N * 4);
    int* off_pa = (int*)alloc((size_t)N * 4);
    int* perm_pa = (int*)alloc((size_t)E * 4);
    int* cnt_ap = (int*)alloc((size_t)N * 4);
    int* off_ap = (int*)alloc((size_t)N * 4);
    int* perm_ap = (int*)alloc((size_t)E * 4);
    int* cursor  = (int*)alloc((size_t)N * 4);
    int* bsum    = (int*)alloc(256 * 4);

    float* h_p1 = regA;
    float* h_a1 = regB;
    float* h_p2 = regA;
    float* h_a2 = regA + (size_t)N * 64;
    float* out_p2 = regB;
    float* out_a2 = regB + (size_t)N * 64;

    const int* src_pa = ei_pa;       // papers
    const int* dst_pa = ei_pa + E;   // authors
    const int* src_ap = ei_ap;       // authors
    const int* dst_ap = ei_ap + E;   // papers

    const int nbScan = cdiv(N, 1024);

    // ================= CSR build (both lists) =================
    hipMemsetAsync(cnt_pa, 0, (size_t)N * 4, stream);
    hist_kernel<<<cdiv(E, 256), 256, 0, stream>>>(dst_pa, cnt_pa, E);
    scan_blk<<<nbScan, 256, 0, stream>>>(cnt_pa, off_pa, bsum, N);
    scan_sums<<<1, 256, 0, stream>>>(bsum, nbScan);
    scan_add<<<nbScan, 256, 0, stream>>>(off_pa, bsum, N);
    hipMemsetAsync(cursor, 0, (size_t)N * 4, stream);
    scatter_perm<<<cdiv(E, 256), 256, 0, stream>>>(src_pa, dst_pa, off_pa, cursor, perm_pa, E);

    hipMemsetAsync(cnt_ap, 0, (size_t)N * 4, stream);
    hist_kernel<<<cdiv(E, 256), 256, 0, stream>>>(dst_ap, cnt_ap, E);
    scan_blk<<<nbScan, 256, 0, stream>>>(cnt_ap, off_ap, bsum, N);
    scan_sums<<<1, 256, 0, stream>>>(bsum, nbScan);
    scan_add<<<nbScan, 256, 0, stream>>>(off_ap, bsum, N);
    hipMemsetAsync(cursor, 0, (size_t)N * 4, stream);
    scatter_perm<<<cdiv(E, 256), 256, 0, stream>>>(src_ap, dst_ap, off_ap, cursor, perm_ap, E);

    // ================= Layer 1 =================
    gemm_bias<128, 128, 8><<<cdiv(NP, 64), 256, 0, stream>>>(x_p, p1W, p1b, h_p1, NP);
    gemm_bias<128, 128, 8><<<cdiv(NA, 64), 256, 0, stream>>>(x_a, a1W, a1b, h_a1, NA);

    node_alpha2<128, 32><<<cdiv((long long)NP * 32, 256), 256, 0, stream>>>(
        h_p1, s1pa, d1ap, asrc_pa, adst_ap, NP);
    node_alpha2<128, 32><<<cdiv((long long)NA * 32, 256), 256, 0, stream>>>(
        h_a1, s1ap, d1pa, asrc_ap, adst_pa, NA);

    // pa: papers -> authors (out_a1); ap: authors -> papers (out_p1)
    csr_attn_agg<128, 32><<<cdiv((long long)N * 32, 256), 256, 0, stream>>>(
        perm_pa, off_pa, cnt_pa, asrc_pa, adst_pa, h_p1, out_a1, N);
    csr_attn_agg<128, 32><<<cdiv((long long)N * 32, 256), 256, 0, stream>>>(
        perm_ap, off_ap, cnt_ap, asrc_ap, adst_ap, h_a1, out_p1, N);

    // ================= Layer 2 =================
    // (out_* are already relu'd by csr_attn_agg)
    gemm_bias<128, 64, 4><<<cdiv(NP, 64), 256, 0, stream>>>(out_p1, p2W, p2b, h_p2, NP);
    gemm_bias<128, 64, 4><<<cdiv(NA, 64), 256, 0, stream>>>(out_a1, a2W, a2b, h_a2, NA);

    node_alpha2<64, 16><<<cdiv((long long)NP * 16, 256), 256, 0, stream>>>(
        h_p2, s2pa, d2ap, asrc_pa, adst_ap, NP);
    node_alpha2<64, 16><<<cdiv((long long)NA * 16, 256), 256, 0, stream>>>(
        h_a2, s2ap, d2pa, asrc_ap, adst_pa, NA);

    csr_attn_agg<64, 16><<<cdiv((long long)N * 16, 256), 256, 0, stream>>>(
        perm_pa, off_pa, cnt_pa, asrc_pa, adst_pa, h_p2, out_a2, N);
    csr_attn_agg<64, 16><<<cdiv((long long)N * 16, 256), 256, 0, stream>>>(
        perm_ap, off_ap, cnt_ap, asrc_ap, adst_ap, h_a2, out_p2, N);

    // ================= Final dot =================
    edge_dot<<<cdiv((long long)L * 16, 256), 256, 0, stream>>>(
        eli, out_p2, out_a2, (float*)d_out, L);
}